// Round 8
// baseline (441.535 us; speedup 1.0000x reference)
//
#include <hip/hip_runtime.h>

// ---------------------------------------------------------------------------
// UpsampleLayer: out = Upsample2x_FIR( W @ x ) + bias.  Upsample and 1x1 conv
// commute -> GEMM at 64x64 then FIR-upsample to 127x127.
//
// R7: FUSED persistent kernel. Block = (s-half sh, o-panel op of 32, batch b).
// Per s-tile (128 spatial = z rows {2ts, 2ts+1}): GEMM 32x128xK512 -> acc ->
// z_lds (f32) -> upsample out rows 4ts-1..4ts+2 using carry row 2ts-1 kept in
// c_lds. z never touches HBM; the 516MB out-write stream overlaps MFMA.
// Upsample math (validated R0-R6): col j: g[j] = tA*z[n0] + tB*z[n0+1],
// n0=(j-1)>>1, even j taps (1,3), odd (3,1), j==0 left tap 0.
// row 2m-1 = 3*g[m-1] + g[m]; row 2m = g[m-1] + 3*g[m]; all * 1/16 + bias.
// ---------------------------------------------------------------------------

#define B_   16
#define CIN  512
#define COUT 512
#define S_   4096   // 64*64
#define HO   127
#define WO   127

typedef unsigned int  u32;
typedef unsigned short u16;
typedef __attribute__((ext_vector_type(8))) short  bf16x8;
typedef __attribute__((ext_vector_type(8))) u16    u16x8;
typedef __attribute__((ext_vector_type(4))) float  f32x4;

static __device__ __forceinline__ u16 f2bf(float f) {
  u32 u = __float_as_uint(f);
  u += 0x7FFFu + ((u >> 16) & 1u);   // RNE (inputs finite)
  return (u16)(u >> 16);
}

#if defined(__has_builtin)
#if __has_builtin(__builtin_amdgcn_global_load_lds)
#define HAS_GLOAD 1
#endif
#endif
#ifndef HAS_GLOAD
#define HAS_GLOAD 0
#endif

#if HAS_GLOAD
static __device__ __forceinline__ void gload16(const char* g, char* l) {
  __builtin_amdgcn_global_load_lds(
      (const __attribute__((address_space(1))) unsigned int*)g,
      (__attribute__((address_space(3))) unsigned int*)l, 16, 0, 0);
}
#endif

// ---------------------------------------------------------------------------
// Tiled operand layout (wt and xt), per 128(row) x 32(k) tile = 8 KiB:
//   tile = 512 units of 16B; unit u = kg*128 + r; unit holds 8 bf16 with
//   k = tk*32 + kg*8 + e.  (Validated by passing GEMM R0-R6.)
// ---------------------------------------------------------------------------

__global__ __launch_bounds__(256) void conv_w_kernel(
    const float* __restrict__ w, u16* __restrict__ wt) {
  int g = blockIdx.x * 256 + threadIdx.x;
  int t_idx = g >> 9;
  int u = g & 511;
  int to = t_idx >> 4, tk = t_idx & 15;
  int r = u & 127, kg = u >> 7;
  int o = to * 128 + r;
  int c = tk * 32 + kg * 8;
  const float4* src = reinterpret_cast<const float4*>(w + (size_t)o * CIN + c);
  float4 lo = src[0], hi = src[1];
  u16x8 pk;
  pk[0] = f2bf(lo.x); pk[1] = f2bf(lo.y); pk[2] = f2bf(lo.z); pk[3] = f2bf(lo.w);
  pk[4] = f2bf(hi.x); pk[5] = f2bf(hi.y); pk[6] = f2bf(hi.z); pk[7] = f2bf(hi.w);
  *reinterpret_cast<u16x8*>(wt + (size_t)g * 8) = pk;
}

__global__ __launch_bounds__(256) void conv_x_kernel(
    const float* __restrict__ x, u16* __restrict__ xt) {
  int ts = blockIdx.x, tk = blockIdx.y, b = blockIdx.z;
  int t = threadIdx.x;
  __shared__ float lf[32 * 128];
  const float* src = x + ((size_t)(b * CIN + tk * 32)) * S_ + ts * 128;
#pragma unroll
  for (int i = 0; i < 4; ++i) {
    int q = i * 256 + t;
    int c = q >> 5, sq = q & 31;
    *reinterpret_cast<float4*>(&lf[c * 128 + sq * 4]) =
        *reinterpret_cast<const float4*>(src + (size_t)c * S_ + sq * 4);
  }
  __syncthreads();
  size_t tile_base = (((size_t)(b * 32 + ts)) * 16 + tk) * 512;
#pragma unroll
  for (int i = 0; i < 2; ++i) {
    int u = i * 256 + t;
    int kg = u >> 7, r = u & 127;
    u16x8 pk;
#pragma unroll
    for (int e = 0; e < 8; ++e) pk[e] = f2bf(lf[(kg * 8 + e) * 128 + r]);
    *reinterpret_cast<u16x8*>(xt + (tile_base + u) * 8) = pk;
  }
}

// LDS carve (dynamic, 74112 B):
//   Wlds  [0, 32768)        2048 units: [tk 16][kg 4][r 32] of 16B
//   Blds  [32768, 49152)    2 k-steps x 512 units
//   z_lds [49152, 65792)    f32 [2 zrow][32 o][65]   (pad col 64)
//   c_lds [65792, 74112)    f32 [32 o][65]           carry z-row 2ts-1
#define WL_OFF 0
#define BL_OFF 32768
#define ZL_OFF 49152
#define CL_OFF 65792
#define SMEM_BYTES 74112

__global__ __launch_bounds__(256) void fused_kernel(
    const u16* __restrict__ wt, const u16* __restrict__ xt,
    const float* __restrict__ bias, float* __restrict__ out) {
  extern __shared__ char smem[];
  char* Wl = smem + WL_OFF;
  char* Bl = smem + BL_OFF;
  float* zl = (float*)(smem + ZL_OFF);   // [2][32*65]
  float* cl = (float*)(smem + CL_OFF);   // [32*65]

  int t = threadIdx.x;
  int sh = blockIdx.x, op = blockIdx.y, b = blockIdx.z;
  int lane = t & 63, wv = t >> 6;
  int lr = lane & 15, kg = lane >> 4;
  int to = op >> 2, opq = op & 3;

  // ---- stage W panel (32 o x 512 c) into Wlds, once ----
#if HAS_GLOAD
#pragma unroll
  for (int u = 0; u < 8; ++u) {
    int L = u * 256 + t;                       // Wlds unit index
    int tk = L >> 7, kq = (L >> 5) & 3, r = L & 31;
    size_t gu = ((size_t)(to * 16 + tk)) * 512 + (size_t)(kq * 128 + opq * 32 + r);
    gload16((const char*)wt + gu * 16, Wl + (size_t)L * 16);
  }
#else
  {
    u16x8 tmp[8];
#pragma unroll
    for (int u = 0; u < 8; ++u) {
      int L = u * 256 + t;
      int tk = L >> 7, kq = (L >> 5) & 3, r = L & 31;
      size_t gu = ((size_t)(to * 16 + tk)) * 512 + (size_t)(kq * 128 + opq * 32 + r);
      tmp[u] = *reinterpret_cast<const u16x8*>((const char*)wt + gu * 16);
    }
#pragma unroll
    for (int u = 0; u < 8; ++u)
      *reinterpret_cast<u16x8*>(Wl + (size_t)(u * 256 + t) * 16) = tmp[u];
  }
#endif
  for (int i = t; i < 2080; i += 256) cl[i] = 0.f;   // carry row = 0
  __syncthreads();

  // upsample thread mapping: o = t&31, row-pair pr = (t>>5)&1, col-quarter q
  int uo = t & 31, pr = (t >> 5) & 1, q = t >> 6;
  int o_glob = op * 32 + uo;
  float bvv = bias[o_glob];
  float* obase = out + ((size_t)b * 512 + o_glob) * (size_t)(HO * WO);

  int st0 = sh * 16;
  // prologue tile (sh==1): compute s-tile st0-1 only to fill the carry row.
  for (int ts = st0 - (sh ? 1 : 0); ts < st0 + 16; ++ts) {
    bool wout = (ts >= st0);

    // ---- GEMM 32(o) x 128(s) x 512(c): 8 stages of BK=64 ----
    f32x4 acc[2][2];
#pragma unroll
    for (int m = 0; m < 2; ++m)
#pragma unroll
      for (int n = 0; n < 2; ++n) acc[m][n] = f32x4{0.f, 0.f, 0.f, 0.f};

    const char* xb = (const char*)xt + ((size_t)(b * 32 + ts) * 16) * 8192;
    for (int k2 = 0; k2 < 8; ++k2) {
      const char* px = xb + (size_t)k2 * 16384;
      __syncthreads();   // previous stage's Bl reads done
#if HAS_GLOAD
#pragma unroll
      for (int qq = 0; qq < 4; ++qq)
        gload16(px + qq * 4096 + t * 16, Bl + qq * 4096 + t * 16);
      __syncthreads();   // drains vmcnt, publishes Bl
#else
      {
        u16x8 tb[4];
#pragma unroll
        for (int qq = 0; qq < 4; ++qq)
          tb[qq] = *reinterpret_cast<const u16x8*>(px + qq * 4096 + t * 16);
        __syncthreads();
#pragma unroll
        for (int qq = 0; qq < 4; ++qq)
          *reinterpret_cast<u16x8*>(Bl + qq * 4096 + t * 16) = tb[qq];
        __syncthreads();
      }
#endif
#pragma unroll
      for (int kk = 0; kk < 2; ++kk) {
        int ks = k2 * 2 + kk;
        bf16x8 av[2], bw[2];
#pragma unroll
        for (int m = 0; m < 2; ++m)
          av[m] = *reinterpret_cast<const bf16x8*>(
              Wl + ks * 2048 + (kg * 32 + m * 16 + lr) * 16);
#pragma unroll
        for (int n = 0; n < 2; ++n)
          bw[n] = *reinterpret_cast<const bf16x8*>(
              Bl + kk * 8192 + (kg * 128 + wv * 32 + n * 16 + lr) * 16);
#pragma unroll
        for (int m = 0; m < 2; ++m)
#pragma unroll
          for (int n = 0; n < 2; ++n)
            acc[m][n] = __builtin_amdgcn_mfma_f32_16x16x32_bf16(
                av[m], bw[n], acc[m][n], 0, 0, 0);
      }
    }

    // ---- acc -> z_lds (f32).  C/D: col=lr (s), row=kg*4+reg (o). ----
    __syncthreads();
#pragma unroll
    for (int m = 0; m < 2; ++m)
#pragma unroll
      for (int n = 0; n < 2; ++n) {
        int s_loc = wv * 32 + n * 16 + lr;
        float* zp = zl + (s_loc >> 6) * 2080 + (s_loc & 63);
#pragma unroll
        for (int r = 0; r < 4; ++r) {
          int o_loc = m * 16 + kg * 4 + r;
          zp[o_loc * 65] = acc[m][n][r];
        }
      }
    __syncthreads();

    // ---- upsample: out rows {4ts-1+2pr, 4ts+2pr}, cols [q*32, q*32+32) ----
    // pr=0: zA = carry (row 2ts-1), zB = z row 2ts
    // pr=1: zA = z row 2ts,         zB = z row 2ts+1
    const float* pA = pr ? (zl + uo * 65) : (cl + uo * 65);
    const float* pB = pr ? (zl + 2080 + uo * 65) : (zl + uo * 65);
    int nlo = q * 16 - 1;
    float zA[18], zB[18];
    zA[0] = (q == 0) ? 0.f : pA[nlo];
    zB[0] = (q == 0) ? 0.f : pB[nlo];
#pragma unroll
    for (int i = 1; i < 18; ++i) { zA[i] = pA[nlo + i]; zB[i] = pB[nlo + i]; }

    int r0 = 4 * ts - 1 + 2 * pr;
    float* p0 = obase + (size_t)r0 * WO + q * 32;
    float* p1 = p0 + WO;
#pragma unroll
    for (int ch = 0; ch < 8; ++ch) {
      float v0[4], v1[4];
#pragma unroll
      for (int e = 0; e < 4; ++e) {
        int jj = ch * 4 + e;        // j = 32q + jj
        int ln = (jj + 1) >> 1;     // z reg index: n0 - (16q-1)
        float tA = (jj & 1) ? 3.f : 1.f;
        float tB = (jj & 1) ? 1.f : 3.f;
        if (q == 0 && jj == 0) tA = 0.f;     // j==0 left tap
        float gA = tA * zA[ln] + tB * zA[ln + 1];
        float gB = tA * zB[ln] + tB * zB[ln + 1];
        v0[e] = fmaf(fmaf(3.f, gA, gB), 0.0625f, bvv);   // row 2m-1
        v1[e] = fmaf(fmaf(3.f, gB, gA), 0.0625f, bvv);   // row 2m
      }
      if (wout) {
        bool tail = (q == 3) && (ch == 7);   // j = 124..127, drop j=127
        if (!tail) {
          if (r0 >= 0) __builtin_memcpy(p0 + ch * 4, v0, 16);
          __builtin_memcpy(p1 + ch * 4, v1, 16);
        } else {
          if (r0 >= 0) { p0[28] = v0[0]; p0[29] = v0[1]; p0[30] = v0[2]; }
          p1[28] = v1[0]; p1[29] = v1[1]; p1[30] = v1[2];
        }
      }
    }
    __syncthreads();
    // carry = z row 2ts+1 for the next s-tile
    for (int i = t; i < 2080; i += 256) cl[i] = zl[2080 + i];
  }
}

// Slow but correct fallback if ws_size is insufficient.
__global__ __launch_bounds__(256) void fallback_kernel(
    const float* __restrict__ x, const float* __restrict__ w,
    const float* __restrict__ bias, float* __restrict__ out) {
  u32 idx = blockIdx.x * 256u + threadIdx.x;
  const u32 total = (u32)B_ * COUT * HO * WO;
  if (idx >= total) return;
  u32 j = idx % WO;
  u32 r1 = idx / WO;
  u32 i = r1 % HO;
  u32 bo = r1 / HO;
  int o = (int)(bo & 511u);
  int b = (int)(bo >> 9);
  int m = (int)(i >> 1), n = (int)(j >> 1);
  int ie = !(i & 1), je = !(j & 1);
  int rA = ie ? m - 1 : m;
  int cA = je ? n - 1 : n;
  float w_r0 = ie ? 1.f : 3.f, w_r1 = ie ? 3.f : 1.f;
  float w_c0 = je ? 1.f : 3.f, w_c1 = je ? 3.f : 1.f;
  const float* xb = x + (size_t)b * CIN * S_;
  float acc = 0.f;
  for (int c = 0; c < CIN; ++c) {
    const float* xc = xb + (size_t)c * S_;
    float y = 0.f;
    if (rA >= 0) {
      if (cA >= 0) y += w_r0 * w_c0 * xc[rA * 64 + cA];
      y += w_r0 * w_c1 * xc[rA * 64 + cA + 1];
    }
    if (cA >= 0) y += w_r1 * w_c0 * xc[(rA + 1) * 64 + cA];
    y += w_r1 * w_c1 * xc[(rA + 1) * 64 + cA + 1];
    acc += y * w[(size_t)o * CIN + c];
  }
  out[idx] = acc * 0.0625f + bias[o];
}

extern "C" void kernel_launch(void* const* d_in, const int* in_sizes, int n_in,
                              void* d_out, int out_size, void* d_ws,
                              size_t ws_size, hipStream_t stream) {
  const float* x = (const float*)d_in[0];
  // d_in[1] = fir_kernel (deterministic, taps hard-coded)
  const float* w = (const float*)d_in[2];
  const float* bias = (const float*)d_in[3];
  float* out = (float*)d_out;

  const size_t xt_bytes = (size_t)B_ * S_ * CIN * 2;   // 64 MiB
  const size_t wt_off = xt_bytes;
  const size_t wt_bytes = (size_t)COUT * CIN * 2;      // 512 KiB
  const size_t need = wt_off + wt_bytes;
  const size_t total_out = (size_t)B_ * COUT * HO * WO;
  const u32 nblk_out = (u32)((total_out + 255) / 256);

  if (ws_size >= need) {
    u16* xt = (u16*)d_ws;
    u16* wt = (u16*)((char*)d_ws + wt_off);
    conv_w_kernel<<<128, 256, 0, stream>>>(w, wt);
    conv_x_kernel<<<dim3(32, 16, B_), 256, 0, stream>>>(x, xt);
    fused_kernel<<<dim3(2, 16, B_), 256, SMEM_BYTES, stream>>>(wt, xt, bias, out);
  } else {
    fallback_kernel<<<nblk_out, 256, 0, stream>>>(x, w, bias, out);
  }
}

// Round 9
// 314.086 us; speedup vs baseline: 1.4058x; 1.4058x over previous
//
#include <hip/hip_runtime.h>

// ---------------------------------------------------------------------------
// UpsampleLayer: out = Upsample2x_FIR( W @ x ) + bias   (upsample and 1x1 conv
// commute, so the GEMM runs at 64x64 instead of 127x127 -> 4x fewer FLOPs).
//
// Shapes: x[16][512][64][64] f32, w[512][512] f32, bias[512] f32 (zeros),
//         out[16][512][127][127] f32.
// Upsample math (validated R0-R7):
//   col j: g[j] = tA*z[n0] + tB*z[n0+1], n0=(j-1)>>1; even j taps (1,3),
//   odd j (3,1); j==0 left tap 0.
//   out row 2m-1 = 3*g[m-1] + g[m]; out row 2m = g[m-1] + 3*g[m]; g[-1]=0;
//   all * 1/16 + bias. Output 127x127.
// History: R1 quad 436->266; R2 LDS scalar-read (LDS-pipe-bound); R3 reg
// row-march 197; R4 +2waves/img 178 (best total 262.8); R5 shfl+nt-asm
// REGRESSED; R6 strided scalar loads ~flat; R7 fused persistent REGRESSED
// (2 blocks/CU latency-bound, MfmaUtil 3.5%).
// R8: recalibrated from R1's VALUBusy: upsample is VALU-ISSUE-bound (~9x my
// inst estimates). New upsample: block per image, z staged in LDS (padded
// stride 66 u16), thread-iter = 16 outputs (2 rows x 8 cols) -> ~6.5
// inst/output; dense 32B stores. GEMM chain = R4 exact (benched best).
// ---------------------------------------------------------------------------

#define B_   16
#define CIN  512
#define COUT 512
#define S_   4096   // 64*64
#define HO   127
#define WO   127

typedef unsigned int  u32;
typedef unsigned short u16;
typedef __attribute__((ext_vector_type(8))) short  bf16x8;
typedef __attribute__((ext_vector_type(8))) u16    u16x8;
typedef __attribute__((ext_vector_type(4))) float  f32x4;

static __device__ __forceinline__ u16 f2bf(float f) {
  u32 u = __float_as_uint(f);
  u += 0x7FFFu + ((u >> 16) & 1u);   // RNE (inputs finite)
  return (u16)(u >> 16);
}
static __device__ __forceinline__ float bf2f(u16 h) {
  return __uint_as_float(((u32)h) << 16);
}

#if defined(__has_builtin)
#if __has_builtin(__builtin_amdgcn_global_load_lds)
#define HAS_GLOAD 1
#endif
#endif
#ifndef HAS_GLOAD
#define HAS_GLOAD 0
#endif

#if HAS_GLOAD
static __device__ __forceinline__ void gload16(const char* g, char* l) {
  __builtin_amdgcn_global_load_lds(
      (const __attribute__((address_space(1))) unsigned int*)g,
      (__attribute__((address_space(3))) unsigned int*)l, 16, 0, 0);
}
#endif

// ---------------------------------------------------------------------------
// Tiled operand layout (wt and xt), per 128(row) x 32(k) tile = 8 KiB:
//   tile = 512 units of 16B; unit u = kg*128 + r; unit holds 8 bf16 with
//   k = tk*32 + kg*8 + e.
// ---------------------------------------------------------------------------

__global__ __launch_bounds__(256) void conv_w_kernel(
    const float* __restrict__ w, u16* __restrict__ wt) {
  int g = blockIdx.x * 256 + threadIdx.x;
  int t_idx = g >> 9;
  int u = g & 511;
  int to = t_idx >> 4, tk = t_idx & 15;
  int r = u & 127, kg = u >> 7;
  int o = to * 128 + r;
  int c = tk * 32 + kg * 8;
  const float4* src = reinterpret_cast<const float4*>(w + (size_t)o * CIN + c);
  float4 lo = src[0], hi = src[1];
  u16x8 pk;
  pk[0] = f2bf(lo.x); pk[1] = f2bf(lo.y); pk[2] = f2bf(lo.z); pk[3] = f2bf(lo.w);
  pk[4] = f2bf(hi.x); pk[5] = f2bf(hi.y); pk[6] = f2bf(hi.z); pk[7] = f2bf(hi.w);
  *reinterpret_cast<u16x8*>(wt + (size_t)g * 8) = pk;
}

__global__ __launch_bounds__(256) void conv_x_kernel(
    const float* __restrict__ x, u16* __restrict__ xt) {
  int ts = blockIdx.x, tk = blockIdx.y, b = blockIdx.z;
  int t = threadIdx.x;
  __shared__ float lf[32 * 128];
  const float* src = x + ((size_t)(b * CIN + tk * 32)) * S_ + ts * 128;
#pragma unroll
  for (int i = 0; i < 4; ++i) {
    int q = i * 256 + t;
    int c = q >> 5, sq = q & 31;
    *reinterpret_cast<float4*>(&lf[c * 128 + sq * 4]) =
        *reinterpret_cast<const float4*>(src + (size_t)c * S_ + sq * 4);
  }
  __syncthreads();
  size_t tile_base = (((size_t)(b * 32 + ts)) * 16 + tk) * 512;
#pragma unroll
  for (int i = 0; i < 2; ++i) {
    int u = i * 256 + t;
    int kg = u >> 7, r = u & 127;
    u16x8 pk;
#pragma unroll
    for (int e = 0; e < 8; ++e) pk[e] = f2bf(lf[(kg * 8 + e) * 128 + r]);
    *reinterpret_cast<u16x8*>(xt + (tile_base + u) * 8) = pk;
  }
}

// GEMM (R4 exact): Z[b][o][s], 128x128 tile, BK=32, 4 waves (2x2),
// each wave 64x64 = 4x4 frags of mfma_f32_16x16x32_bf16.
__global__ __launch_bounds__(256) void gemm_kernel(
    const u16* __restrict__ wt, const u16* __restrict__ xt,
    u16* __restrict__ z) {
  int nt = blockIdx.x, mt = blockIdx.y, b = blockIdx.z;
  int t = threadIdx.x;
  __shared__ short lds[8192];
  char* lA = (char*)&lds[0];
  char* lB = lA + 8192;

  int lane = t & 63, wid = t >> 6;
  int wr = wid >> 1, wc = wid & 1;
  int lr = lane & 15, kg = lane >> 4;

  f32x4 acc[4][4];
#pragma unroll
  for (int m = 0; m < 4; ++m)
#pragma unroll
    for (int n = 0; n < 4; ++n) acc[m][n] = f32x4{0.f, 0.f, 0.f, 0.f};

  const char* gA = (const char*)wt + (size_t)(mt * 16) * 8192;
  const char* gB = (const char*)xt + ((size_t)(b * 32 + nt)) * 16 * 8192;

  int abyte[4], bbyte[4];
#pragma unroll
  for (int m = 0; m < 4; ++m) abyte[m] = (kg * 128 + wr * 64 + m * 16 + lr) * 16;
#pragma unroll
  for (int n = 0; n < 4; ++n) bbyte[n] = (kg * 128 + wc * 64 + n * 16 + lr) * 16;

  for (int ks = 0; ks < 16; ++ks) {
    const char* pA = gA + (size_t)ks * 8192;
    const char* pB = gB + (size_t)ks * 8192;
#if HAS_GLOAD
    __syncthreads();
    gload16(pA + t * 16, lA + t * 16);
    gload16(pA + 4096 + t * 16, lA + 4096 + t * 16);
    gload16(pB + t * 16, lB + t * 16);
    gload16(pB + 4096 + t * 16, lB + 4096 + t * 16);
    __syncthreads();
#else
    u16x8 va0 = *reinterpret_cast<const u16x8*>(pA + t * 16);
    u16x8 va1 = *reinterpret_cast<const u16x8*>(pA + 4096 + t * 16);
    u16x8 vb0 = *reinterpret_cast<const u16x8*>(pB + t * 16);
    u16x8 vb1 = *reinterpret_cast<const u16x8*>(pB + 4096 + t * 16);
    __syncthreads();
    *reinterpret_cast<u16x8*>(lA + t * 16) = va0;
    *reinterpret_cast<u16x8*>(lA + 4096 + t * 16) = va1;
    *reinterpret_cast<u16x8*>(lB + t * 16) = vb0;
    *reinterpret_cast<u16x8*>(lB + 4096 + t * 16) = vb1;
    __syncthreads();
#endif
    bf16x8 av[4], bv[4];
#pragma unroll
    for (int m = 0; m < 4; ++m)
      av[m] = *reinterpret_cast<const bf16x8*>(lA + abyte[m]);
#pragma unroll
    for (int n = 0; n < 4; ++n)
      bv[n] = *reinterpret_cast<const bf16x8*>(lB + bbyte[n]);
#pragma unroll
    for (int m = 0; m < 4; ++m)
#pragma unroll
      for (int n = 0; n < 4; ++n)
        acc[m][n] = __builtin_amdgcn_mfma_f32_16x16x32_bf16(
            av[m], bv[n], acc[m][n], 0, 0, 0);
  }

  int o_b = mt * 128 + wr * 64 + kg * 4;
  int s_b = nt * 128 + wc * 64 + lr;
#pragma unroll
  for (int m = 0; m < 4; ++m)
#pragma unroll
    for (int n = 0; n < 4; ++n) {
      f32x4 v = acc[m][n];
      size_t base = ((size_t)(b * COUT + o_b + m * 16)) * S_ + (s_b + n * 16);
#pragma unroll
      for (int r = 0; r < 4; ++r) z[base + (size_t)r * S_] = f2bf(v[r]);
    }
}

// R8 upsample: one block per (b,o) image. z (8KB) staged in LDS with padded
// row stride 66 u16 (132B -> 2-way max bank aliasing). Thread = (col-chunk
// c = t&15 -> out cols [8c,8c+8), m-row mr = t>>4); 4 iterations over
// m = 16*it + mr. Per iteration: 12 LDS u16 reads (rows m-1, m; cols
// 4c-1..4c+4), 16 outputs (rows 2m-1, 2m), dense 32B row-chunk stores.
#define ZSTRIDE 66
__global__ __launch_bounds__(256) void upsample_kernel(
    const u16* __restrict__ z, const float* __restrict__ bias,
    float* __restrict__ out) {
  int bo = blockIdx.x;  // b*512 + o
  int t = threadIdx.x;
  __shared__ u16 zl[64 * ZSTRIDE];

  // stage: 512 items of 8 u16 (global u16x8 aligned loads)
  {
    const u16x8* src = reinterpret_cast<const u16x8*>(z + ((size_t)bo << 12));
    u16x8 v0 = src[t];
    u16x8 v1 = src[t + 256];
    int r0 = t >> 3, c0 = (t & 7) * 8;
    int r1 = (t + 256) >> 3, c1 = (t & 7) * 8;  // (t+256)&7 == t&7
    u16* p0 = &zl[r0 * ZSTRIDE + c0];
    u16* p1 = &zl[r1 * ZSTRIDE + c1];
#pragma unroll
    for (int e = 0; e < 8; ++e) { p0[e] = (u16)v0[e]; p1[e] = (u16)v1[e]; }
  }
  float bv = bias[bo & 511];
  __syncthreads();

  int c = t & 15;   // col chunk
  int mr = t >> 4;  // 0..15
  float* ob = out + (size_t)bo * (HO * WO) + 8 * c;
  int n0 = 4 * c - 1;
  int i0 = (c == 0) ? 0 : n0;  // clamped first col (value masked by tap 0)

  for (int it = 0; it < 4; ++it) {
    int m = it * 16 + mr;
    const u16* rA = &zl[((m == 0) ? 0 : (m - 1)) * ZSTRIDE];
    const u16* rB = &zl[m * ZSTRIDE];
    float a[6], d[6];
    a[0] = bf2f(rA[i0]); d[0] = bf2f(rB[i0]);
#pragma unroll
    for (int k = 1; k < 6; ++k) {
      a[k] = bf2f(rA[n0 + k]);
      d[k] = bf2f(rB[n0 + k]);
    }
    float wa = (m == 0) ? 0.f : 1.f;  // g[-1] = 0

    float v0[8], v1[8];
#pragma unroll
    for (int e = 0; e < 8; ++e) {
      // j = 8c+e; local tap index li = (e==0) ? 0 : 1 + ((e-1)>>1)
      int li = (e == 0) ? 0 : (1 + ((e - 1) >> 1));
      float tA = (e & 1) ? 3.f : 1.f;
      float tB = (e & 1) ? 1.f : 3.f;
      if (c == 0 && e == 0) tA = 0.f;  // j==0 left tap
      float gA = wa * (tA * a[li] + tB * a[li + 1]);
      float gB = tA * d[li] + tB * d[li + 1];
      v0[e] = fmaf(fmaf(3.f, gA, gB), 0.0625f, bv);  // row 2m-1
      v1[e] = fmaf(fmaf(3.f, gB, gA), 0.0625f, bv);  // row 2m
    }

    float* p1p = ob + (size_t)(2 * m) * WO;
    float* p0p = p1p - WO;
    if (c < 15) {
      if (m > 0) __builtin_memcpy(p0p, v0, 32);
      __builtin_memcpy(p1p, v1, 32);
    } else {  // cols 120..126 (7 valid)
      if (m > 0) {
        __builtin_memcpy(p0p, v0, 16);
        __builtin_memcpy(p0p + 4, &v0[4], 8);
        p0p[6] = v0[6];
      }
      __builtin_memcpy(p1p, v1, 16);
      __builtin_memcpy(p1p + 4, &v1[4], 8);
      p1p[6] = v1[6];
    }
  }
}

// Slow but correct fallback if ws_size is insufficient.
__global__ __launch_bounds__(256) void fallback_kernel(
    const float* __restrict__ x, const float* __restrict__ w,
    const float* __restrict__ bias, float* __restrict__ out) {
  u32 idx = blockIdx.x * 256u + threadIdx.x;
  const u32 total = (u32)B_ * COUT * HO * WO;
  if (idx >= total) return;
  u32 j = idx % WO;
  u32 r1 = idx / WO;
  u32 i = r1 % HO;
  u32 bo = r1 / HO;
  int o = (int)(bo & 511u);
  int b = (int)(bo >> 9);
  int m = (int)(i >> 1), n = (int)(j >> 1);
  int ie = !(i & 1), je = !(j & 1);
  int rA = ie ? m - 1 : m;
  int cA = je ? n - 1 : n;
  float w_r0 = ie ? 1.f : 3.f, w_r1 = ie ? 3.f : 1.f;
  float w_c0 = je ? 1.f : 3.f, w_c1 = je ? 3.f : 1.f;
  const float* xb = x + (size_t)b * CIN * S_;
  float acc = 0.f;
  for (int cc = 0; cc < CIN; ++cc) {
    const float* xc = xb + (size_t)cc * S_;
    float y = 0.f;
    if (rA >= 0) {
      if (cA >= 0) y += w_r0 * w_c0 * xc[rA * 64 + cA];
      y += w_r0 * w_c1 * xc[rA * 64 + cA + 1];
    }
    if (cA >= 0) y += w_r1 * w_c0 * xc[(rA + 1) * 64 + cA];
    y += w_r1 * w_c1 * xc[(rA + 1) * 64 + cA + 1];
    acc += y * w[(size_t)o * CIN + cc];
  }
  out[idx] = acc * 0.0625f + bias[o];
}

extern "C" void kernel_launch(void* const* d_in, const int* in_sizes, int n_in,
                              void* d_out, int out_size, void* d_ws,
                              size_t ws_size, hipStream_t stream) {
  const float* x = (const float*)d_in[0];
  // d_in[1] = fir_kernel (deterministic, taps hard-coded)
  const float* w = (const float*)d_in[2];
  const float* bias = (const float*)d_in[3];
  float* out = (float*)d_out;

  const size_t xt_bytes = (size_t)B_ * S_ * CIN * 2;       // 64 MiB
  const size_t wt_off = xt_bytes;
  const size_t wt_bytes = (size_t)COUT * CIN * 2;          // 512 KiB
  const size_t z_off = wt_off + ((wt_bytes + 255) & ~(size_t)255);
  const size_t need = z_off + (size_t)B_ * COUT * S_ * 2;  // ~128.5 MiB
  const size_t total_out = (size_t)B_ * COUT * HO * WO;
  const u32 nblk_out = (u32)((total_out + 255) / 256);

  if (ws_size >= need) {
    u16* xt = (u16*)d_ws;
    u16* wt = (u16*)((char*)d_ws + wt_off);
    u16* zz = (u16*)((char*)d_ws + z_off);
    conv_w_kernel<<<128, 256, 0, stream>>>(w, wt);
    conv_x_kernel<<<dim3(32, 16, B_), 256, 0, stream>>>(x, xt);
    gemm_kernel<<<dim3(32, 4, B_), 256, 0, stream>>>(wt, xt, zz);
    upsample_kernel<<<B_ * COUT, 256, 0, stream>>>(zz, bias, out);
  } else {
    fallback_kernel<<<nblk_out, 256, 0, stream>>>(x, w, bias, out);
  }
}